// Round 1
// baseline (119.060 us; speedup 1.0000x reference)
//
#include <hip/hip_runtime.h>
#include <math.h>

namespace {

constexpr int BATCH = 4;
constexpr int H_IN  = 14;
constexpr int W_IN  = 14;
constexpr int ICAP  = 32;
constexpr int OCAP  = 32;
constexpr int SOUT  = 12;   // (14-3)/1+1
constexpr int NI    = 288;  // 3*3*32
constexpr int PD    = 16;   // 4x4 pose
constexpr float EPSF = 1e-9f;

__global__ __launch_bounds__(256, 2)
void caps_em_kernel(const float* __restrict__ pose_in,   // [4,14,14,32,16]
                    const float* __restrict__ act_in,    // [4,14,14,32]
                    const float* __restrict__ wmat,      // [288,32,4,4]
                    const float* __restrict__ beta_v,    // [32]
                    const float* __restrict__ beta_a,    // [32]
                    float* __restrict__ out)             // pose[4,12,12,32,16] ++ act[4,12,12,32]
{
    __shared__ __align__(16) float sP[NI][PD];      // 18 KB patch poses
    __shared__ float sA[NI];                        // patch activations
    __shared__ float sMean[OCAP][PD + 1];           // padded: conflict-free per-o reads
    __shared__ float sInv2[OCAP][PD + 1];           // 1/(2*var)
    __shared__ float sLogSigSum[OCAP];
    __shared__ float sLogAct[OCAP];
    __shared__ float sOAct[OCAP];
    __shared__ float sS0[OCAP];
    __shared__ float sRedS[4][OCAP][2 * PD + 1];    // per-wave partial S1|S2, padded
    __shared__ float sRed0[4][OCAP];                // per-wave partial S0

    const int n  = blockIdx.x;          // 0..575 = b*144 + y*12 + x
    const int b  = n / (SOUT * SOUT);
    const int yx = n % (SOUT * SOUT);
    const int y  = yx / SOUT;
    const int x  = yx % SOUT;

    const int t    = threadIdx.x;       // 0..255
    const int lane = t & 63;
    const int wave = t >> 6;            // 0..3
    const int o    = lane & 31;         // output capsule owned by this lane
    const int half = lane >> 5;         // 0/1: two input caps per wave-step

    // ---- stage 3x3 patch of poses + activations into LDS ----
    for (int k = 0; k < 9; ++k) {
        const int ki = k / 3, kj = k % 3;
        const int cell = (b * H_IN + (y + ki)) * W_IN + (x + kj);
        const float2* srcp = reinterpret_cast<const float2*>(pose_in + (size_t)cell * (ICAP * PD));
        float2* dst = reinterpret_cast<float2*>(&sP[k * ICAP][0]);
        dst[t] = srcp[t];                               // 256 * 8B = 512 floats
        if (t < ICAP) sA[k * ICAP + t] = act_in[(size_t)cell * ICAP + t];
    }
    __syncthreads();

    // 3 fused sweeps: sweep s computes stats of EM iteration s.
    // Sweeps 1,2 first derive rr (softmax over o of zz from previous stats)
    // per input capsule, then accumulate into the next M-step sums.
    for (int sweep = 0; sweep < 3; ++sweep) {
        float s1[PD], s2[PD];
        float s0 = 0.f;
        #pragma unroll
        for (int d = 0; d < PD; ++d) { s1[d] = 0.f; s2[d] = 0.f; }

        for (int step = 0; step < NI / 8; ++step) {
            const int i = step * 8 + wave * 2 + half;   // covers 0..287 uniquely

            float P[PD], W[PD];
            #pragma unroll
            for (int q4 = 0; q4 < 4; ++q4) {            // LDS broadcast within half
                const float4 pv = *reinterpret_cast<const float4*>(&sP[i][q4 * 4]);
                P[q4*4+0] = pv.x; P[q4*4+1] = pv.y; P[q4*4+2] = pv.z; P[q4*4+3] = pv.w;
            }
            const float* wr = wmat + ((size_t)i * OCAP + o) * PD;
            #pragma unroll
            for (int q4 = 0; q4 < 4; ++q4) {            // wave reads 4KB contiguous
                const float4 wv = *reinterpret_cast<const float4*>(&wr[q4 * 4]);
                W[q4*4+0] = wv.x; W[q4*4+1] = wv.y; W[q4*4+2] = wv.z; W[q4*4+3] = wv.w;
            }
            // votes[i,o,p,r] = sum_q P[p,q] * W[q,r]
            float v[PD];
            #pragma unroll
            for (int p = 0; p < 4; ++p) {
                #pragma unroll
                for (int r = 0; r < 4; ++r) {
                    float acc = P[p*4+0] * W[r];
                    acc = fmaf(P[p*4+1], W[4+r],  acc);
                    acc = fmaf(P[p*4+2], W[8+r],  acc);
                    acc = fmaf(P[p*4+3], W[12+r], acc);
                    v[p*4+r] = acc;
                }
            }

            float rrp;
            if (sweep == 0) {
                rrp = sA[i] * (1.0f / 32.0f);           // uniform rr = 1/O
            } else {
                // o_p from previous-iteration stats, then softmax over o
                float ts = 0.f;
                #pragma unroll
                for (int d = 0; d < PD; ++d) {
                    const float diff = v[d] - sMean[o][d];
                    ts = fmaf(diff * diff, sInv2[o][d], ts);
                }
                float zz = sLogAct[o] - ts - sLogSigSum[o];
                float m = zz;
                #pragma unroll
                for (int msk = 16; msk >= 1; msk >>= 1)
                    m = fmaxf(m, __shfl_xor(m, msk, 32));
                const float e = __expf(zz - m);
                float es = e;
                #pragma unroll
                for (int msk = 16; msk >= 1; msk >>= 1)
                    es += __shfl_xor(es, msk, 32);
                rrp = (e / es) * sA[i];                 // rr * i_act
            }

            s0 += rrp;
            #pragma unroll
            for (int d = 0; d < PD; ++d) {
                s1[d] = fmaf(rrp, v[d], s1[d]);
                s2[d] = fmaf(rrp * v[d], v[d], s2[d]);
            }
        }

        // fold the two halves (same o) within each wave
        #pragma unroll
        for (int d = 0; d < PD; ++d) {
            s1[d] += __shfl_xor(s1[d], 32, 64);
            s2[d] += __shfl_xor(s2[d], 32, 64);
        }
        s0 += __shfl_xor(s0, 32, 64);

        if (half == 0) {
            #pragma unroll
            for (int d = 0; d < PD; ++d) {
                sRedS[wave][o][d]      = s1[d];
                sRedS[wave][o][PD + d] = s2[d];
            }
            sRed0[wave][o] = s0;
        }
        __syncthreads();

        if (t < OCAP)
            sS0[t] = sRed0[0][t] + sRed0[1][t] + sRed0[2][t] + sRed0[3][t];
        __syncthreads();

        // ---- M-step stats + activation: 256 threads over (o, d-pair) ----
        {
            const int oo    = t >> 3;           // 0..31
            const int dbase = (t & 7) * 2;      // 0,2,..,14
            const float s0t    = sS0[oo];
            const float inv_s0 = 1.0f / s0t;
            float lsum = 0.f;
            float meanv[2];
            #pragma unroll
            for (int j = 0; j < 2; ++j) {
                const int d = dbase + j;
                const float S1t = sRedS[0][oo][d] + sRedS[1][oo][d]
                                + sRedS[2][oo][d] + sRedS[3][oo][d];
                const float S2t = sRedS[0][oo][PD+d] + sRedS[1][oo][PD+d]
                                + sRedS[2][oo][PD+d] + sRedS[3][oo][PD+d];
                const float mean = S1t * inv_s0;
                float var = fmaf(-mean, mean, S2t * inv_s0);  // E[v^2] - m^2
                var = fmaxf(var, 0.f);
                const float sig = sqrtf(var);
                lsum += __logf(sig + EPSF);
                sMean[oo][d] = mean;
                sInv2[oo][d] = 0.5f / fmaxf(var, 1e-30f);     // 1/(2*sigma^2)
                meanv[j] = mean;
            }
            float ltot = lsum;                   // sum_d log(sigma+EPS) over 8 lanes
            ltot += __shfl_xor(ltot, 1, 8);
            ltot += __shfl_xor(ltot, 2, 8);
            ltot += __shfl_xor(ltot, 4, 8);
            if ((t & 7) == 0) {
                sLogSigSum[oo] = ltot;
                const float cost    = s0t * fmaf(16.f, beta_v[oo], ltot);
                const float invtemp = 1.0f + (float)sweep;     // 1,2,3
                const float zact    = invtemp * (beta_a[oo] - cost);
                const float oact    = 1.0f / (1.0f + __expf(-zact));
                sOAct[oo]   = oact;
                sLogAct[oo] = __logf(oact + EPSF);
            }
            if (sweep == 2) {                    // final pose output
                float* outp = out + (size_t)n * (OCAP * PD);
                outp[oo * PD + dbase]     = meanv[0];
                outp[oo * PD + dbase + 1] = meanv[1];
            }
        }
        __syncthreads();
        if (sweep == 2 && t < OCAP)
            out[(size_t)BATCH * SOUT * SOUT * OCAP * PD + (size_t)n * OCAP + t] = sOAct[t];
    }
}

} // namespace

extern "C" void kernel_launch(void* const* d_in, const int* in_sizes, int n_in,
                              void* d_out, int out_size, void* d_ws, size_t ws_size,
                              hipStream_t stream) {
    const float* pose_in = (const float*)d_in[0];
    const float* act_in  = (const float*)d_in[1];
    const float* wmat    = (const float*)d_in[2];
    const float* beta_v  = (const float*)d_in[3];
    const float* beta_a  = (const float*)d_in[4];
    float* out = (float*)d_out;

    dim3 grid(BATCH * SOUT * SOUT);   // 576 positions
    dim3 block(256);
    caps_em_kernel<<<grid, block, 0, stream>>>(pose_in, act_in, wmat, beta_v, beta_a, out);
}